// Round 12
// baseline (2231.206 us; speedup 1.0000x reference)
//
#include <hip/hip_runtime.h>

#define Bz 32
#define Tz 64
#define Sz 400
#define Dz 512
#define G3 1536
#define VOC 32000
#define NEGC 1e12f
#define SB 50          // s-rows per block
#define JB 8           // blocks per batch element

typedef __attribute__((ext_vector_type(8))) short short8;
typedef __attribute__((ext_vector_type(8))) _Float16 h8;
typedef __attribute__((ext_vector_type(4))) float f32x4;
typedef __attribute__((ext_vector_type(4))) unsigned u32x4;
typedef __attribute__((ext_vector_type(2))) _Float16 half2_t;

__device__ __forceinline__ float sigm(float x){ return 1.f/(1.f+__expf(-x)); }
__device__ __forceinline__ float tanhfast(float x){ float e=__expf(2.f*x); return 1.f - 2.f/(e+1.f); }
__device__ __forceinline__ unsigned short f2bf(float f){
  unsigned int u = __float_as_uint(f);
  u = (u + 0x7FFFu + ((u>>16)&1u)) >> 16;
  return (unsigned short)u;
}
__device__ __forceinline__ unsigned f2bf2(float a, float b){
  return (unsigned)f2bf(a) | ((unsigned)f2bf(b) << 16);
}
__device__ __forceinline__ half2_t bch2(unsigned u){ return __builtin_bit_cast(half2_t, u); }
__device__ __forceinline__ unsigned packh2(float a, float b){
  unsigned short ua = __builtin_bit_cast(unsigned short, (_Float16)a);
  unsigned short ub = __builtin_bit_cast(unsigned short, (_Float16)b);
  return (unsigned)ua | ((unsigned)ub << 16);
}

// ---- agent-scope coherent accessors (bypass stale L2 on BOTH sides; r7-proven
// correct under harness poison+replay — plain consumer loads are NOT safe)
__device__ __forceinline__ float aload_f(const float* p){
  unsigned v = __hip_atomic_load((unsigned*)p, __ATOMIC_RELAXED, __HIP_MEMORY_SCOPE_AGENT);
  return __uint_as_float(v);
}
__device__ __forceinline__ float2 aload_f2(const float* p){
  unsigned long long v = __hip_atomic_load((unsigned long long*)p, __ATOMIC_RELAXED, __HIP_MEMORY_SCOPE_AGENT);
  union { unsigned long long u; float2 f; } c; c.u = v; return c.f;
}
__device__ __forceinline__ void astore_f(float* p, float v){
  __hip_atomic_store((unsigned*)p, __float_as_uint(v), __ATOMIC_RELAXED, __HIP_MEMORY_SCOPE_AGENT);
}
__device__ __forceinline__ int aload_i(const unsigned* p){
  return (int)__hip_atomic_load(p, __ATOMIC_RELAXED, __HIP_MEMORY_SCOPE_AGENT);
}

#if defined(__has_builtin)
#if __has_builtin(__builtin_amdgcn_fdot2)
#define HAVE_FDOT2 1
#endif
#endif
#ifdef HAVE_FDOT2
__device__ __forceinline__ float FDOT(half2_t a, half2_t b, float c){
  return __builtin_amdgcn_fdot2(a, b, c, false);
}
#else
__device__ __forceinline__ float FDOT(half2_t a, half2_t b, float c){
  return c + (float)a[0]*(float)b[0] + (float)a[1]*(float)b[1];
}
#endif

// ---------------- repack emb: (b,t,e) -> emb2 f16 (t*B+b,e) + rin_bf bf16 ----
__global__ __launch_bounds__(128) void repack_emb(const float* __restrict__ emb,
    unsigned short* __restrict__ emb2, unsigned short* __restrict__ rinb){
  int tb = blockIdx.x; int t = tb >> 5, b = tb & 31;
  int e4 = threadIdx.x;
  float4 v = *(const float4*)&emb[((size_t)b*Tz + t)*Dz + e4*4];
  unsigned* e2 = (unsigned*)&emb2[(size_t)tb*Dz + e4*4];
  e2[0] = packh2(v.x, v.y);
  e2[1] = packh2(v.z, v.w);
  unsigned* rb = (unsigned*)&rinb[(size_t)tb*G3 + e4*4];
  rb[0] = f2bf2(v.x, v.y);
  rb[1] = f2bf2(v.z, v.w);
}

// ---- GRU weights, k-slice layout: Wg[((k*6+s)*8+oct)*32 + i] = f16x2 of e=(oct*32+i)*2
__global__ __launch_bounds__(256) void wgj_pack(const float* __restrict__ W_ih,
    const float* __restrict__ W_hh, unsigned* __restrict__ Wg){
  int idx = blockIdx.x*256 + threadIdx.x;   // 512*6*256 = 786432
  int i = idx & 31, oct = (idx>>5)&7;
  int ks = idx >> 8;
  int s = ks % 6, k = ks / 6;
  int e0 = (oct*32 + i)*2;
  float w0, w1;
  if (s < 3){
    const float* base = W_ih + ((size_t)(s*512 + k))*1024 + 512;
    w0 = base[e0]; w1 = base[e0+1];
  } else {
    const float* base = W_hh + ((size_t)((s-3)*512 + k))*512;
    w0 = base[e0]; w1 = base[e0+1];
  }
  Wg[idx] = packh2(w0, w1);
}

// ---- W_q slice layout (JB=8): Wq2[(js*32+i)*512 + jj] = f16x2 of W_q[jj][js*64+2i ..+1]
__global__ __launch_bounds__(256) void wq2_pack(const float* __restrict__ W_q,
    unsigned* __restrict__ Wq2){
  int idx = blockIdx.x*256 + threadIdx.x;   // 131072
  int jj = idx & 511;
  int i  = (idx>>9) & 31;
  int js = idx >> 14;
  int k0 = js*64 + 2*i;
  Wq2[idx] = packh2(W_q[(size_t)jj*512 + k0], W_q[(size_t)jj*512 + k0 + 1]);
}

__global__ __launch_bounds__(256) void cast_f16(const float* __restrict__ in,
    unsigned short* __restrict__ out, int n){
  for (int i = blockIdx.x*256 + threadIdx.x; i < n; i += gridDim.x*256)
    out[i] = __builtin_bit_cast(unsigned short, (_Float16)in[i]);
}

// strided f16 cast: out[r*cols+c] = f16(in[r*ldi + c])
__global__ __launch_bounds__(256) void cast_f16_str(const float* __restrict__ in, int ldi,
    unsigned short* __restrict__ out, int cols, int n){
  for (int i = blockIdx.x*256 + threadIdx.x; i < n; i += gridDim.x*256){
    int r = i / cols, c = i - r*cols;
    out[i] = __builtin_bit_cast(unsigned short, (_Float16)in[(size_t)r*ldi + c]);
  }
}

__global__ __launch_bounds__(256) void cast_bf(const float* __restrict__ in,
    unsigned short* __restrict__ out, int n){
  for (int i = blockIdx.x*256 + threadIdx.x; i < n; i += gridDim.x*256)
    out[i] = f2bf(in[i]);
}

__global__ __launch_bounds__(256) void zero_u32(unsigned* __restrict__ p, int n){
  int i = blockIdx.x*256 + threadIdx.x;
  if (i < n) p[i] = 0u;
}

// ---------------- f32 tiled GEMM (only tiny h0 uses it now) ------------------
__global__ __launch_bounds__(256) void gemm_f32(const float* __restrict__ A, int lda,
    const float* __restrict__ Bm, int ldb, const float* __restrict__ bias,
    float* __restrict__ C, int ldc, int M, int N, int K){
  __shared__ __align__(16) float As[16][68];
  __shared__ __align__(16) float Bs[16][68];
  int tid = threadIdx.x;
  int m0 = blockIdx.x * 64, n0 = blockIdx.y * 64;
  int tx = tid & 15, ty = tid >> 4;
  float acc[4][4] = {};
  int lr = tid >> 2;
  int lk = (tid & 3) << 2;
  for (int k0 = 0; k0 < K; k0 += 16){
    int m = m0 + lr;
    float4 va = (m < M) ? *(const float4*)&A[(size_t)m*lda + k0 + lk] : make_float4(0,0,0,0);
    int n = n0 + lr;
    float4 vb = (n < N) ? *(const float4*)&Bm[(size_t)n*ldb + k0 + lk] : make_float4(0,0,0,0);
    As[lk+0][lr]=va.x; As[lk+1][lr]=va.y; As[lk+2][lr]=va.z; As[lk+3][lr]=va.w;
    Bs[lk+0][lr]=vb.x; Bs[lk+1][lr]=vb.y; Bs[lk+2][lr]=vb.z; Bs[lk+3][lr]=vb.w;
    __syncthreads();
    #pragma unroll
    for (int kk = 0; kk < 16; kk++){
      float4 a = *(const float4*)&As[kk][ty*4];
      float4 b = *(const float4*)&Bs[kk][tx*4];
      float av[4] = {a.x,a.y,a.z,a.w};
      float bv[4] = {b.x,b.y,b.z,b.w};
      #pragma unroll
      for (int i = 0; i < 4; i++)
        #pragma unroll
        for (int j = 0; j < 4; j++)
          acc[i][j] += av[i]*bv[j];
    }
    __syncthreads();
  }
  #pragma unroll
  for (int i = 0; i < 4; i++){
    int m = m0 + ty*4 + i;
    if (m >= M) continue;
    #pragma unroll
    for (int j = 0; j < 4; j++){
      int n = n0 + tx*4 + j;
      if (n < N) C[(size_t)m*ldc + n] = acc[i][j] + bias[n];
    }
  }
}

// ---------------- bf16 MFMA GEMM: out = A_bf @ B_bf^T + bias ----------------
__global__ __launch_bounds__(256) void mfma_bf16(const unsigned short* __restrict__ A, int lda,
    const unsigned short* __restrict__ Bm, int ldb, const float* __restrict__ bias,
    float* __restrict__ out, int N, int K, int mode, int Vext){
  __shared__ __align__(16) unsigned short As[128][40];
  __shared__ __align__(16) unsigned short Bs[128][40];
  int tid = threadIdx.x;
  int m0 = blockIdx.x * 128, n0 = blockIdx.y * 128;
  int wid = tid >> 6, lane = tid & 63;
  int wm = (wid >> 1) * 64, wn = (wid & 1) * 64;
  f32x4 acc[4][4];
  #pragma unroll
  for (int r = 0; r < 4; r++)
    #pragma unroll
    for (int c = 0; c < 4; c++) acc[r][c] = (f32x4){0.f,0.f,0.f,0.f};
  int lr = tid >> 1;
  int lk = (tid & 1) * 16;
  int frow = lane & 15, kg = (lane >> 4) * 8;
  for (int k0 = 0; k0 < K; k0 += 32){
    *(uint4*)&As[lr][lk]     = *(const uint4*)&A[(size_t)(m0+lr)*lda + k0 + lk];
    *(uint4*)&As[lr][lk+8]   = *(const uint4*)&A[(size_t)(m0+lr)*lda + k0 + lk + 8];
    *(uint4*)&Bs[lr][lk]     = *(const uint4*)&Bm[(size_t)(n0+lr)*ldb + k0 + lk];
    *(uint4*)&Bs[lr][lk+8]   = *(const uint4*)&Bm[(size_t)(n0+lr)*ldb + k0 + lk + 8];
    __syncthreads();
    short8 af[4], bf[4];
    #pragma unroll
    for (int r = 0; r < 4; r++) af[r] = *(const short8*)&As[wm + r*16 + frow][kg];
    #pragma unroll
    for (int c = 0; c < 4; c++) bf[c] = *(const short8*)&Bs[wn + c*16 + frow][kg];
    #pragma unroll
    for (int r = 0; r < 4; r++)
      #pragma unroll
      for (int c = 0; c < 4; c++)
        acc[r][c] = __builtin_amdgcn_mfma_f32_16x16x32_bf16(af[r], bf[c], acc[r][c], 0, 0, 0);
    __syncthreads();
  }
  int crow = (lane >> 4) * 4, ccol = lane & 15;
  #pragma unroll
  for (int r = 0; r < 4; r++)
    #pragma unroll
    for (int c = 0; c < 4; c++)
      #pragma unroll
      for (int i = 0; i < 4; i++){
        int m = m0 + wm + r*16 + crow + i;
        int n = n0 + wn + c*16 + ccol;
        float v = acc[r][c][i] + bias[n];
        if (mode == 0){
          out[(size_t)m*N + n] = v;
        } else {
          int b = m & 31, t = m >> 5;
          v = (v == 0.f) ? -NEGC : v;
          out[((size_t)(b*Tz + t))*Vext + n] = v;
        }
      }
}

// ---------------- f16 MFMA GEMM: out = A_h @ B_h^T + bias -------------------
// mode 0: f32 out; mode 2: f16 (u16) out
__global__ __launch_bounds__(256) void mfma_f16k(const unsigned short* __restrict__ A, int lda,
    const unsigned short* __restrict__ Bm, int ldb, const float* __restrict__ bias,
    void* __restrict__ outp, int N, int K, int mode){
  __shared__ __align__(16) unsigned short As[128][40];
  __shared__ __align__(16) unsigned short Bs[128][40];
  int tid = threadIdx.x;
  int m0 = blockIdx.x * 128, n0 = blockIdx.y * 128;
  int wid = tid >> 6, lane = tid & 63;
  int wm = (wid >> 1) * 64, wn = (wid & 1) * 64;
  f32x4 acc[4][4];
  #pragma unroll
  for (int r = 0; r < 4; r++)
    #pragma unroll
    for (int c = 0; c < 4; c++) acc[r][c] = (f32x4){0.f,0.f,0.f,0.f};
  int lr = tid >> 1;
  int lk = (tid & 1) * 16;
  int frow = lane & 15, kg = (lane >> 4) * 8;
  for (int k0 = 0; k0 < K; k0 += 32){
    *(uint4*)&As[lr][lk]     = *(const uint4*)&A[(size_t)(m0+lr)*lda + k0 + lk];
    *(uint4*)&As[lr][lk+8]   = *(const uint4*)&A[(size_t)(m0+lr)*lda + k0 + lk + 8];
    *(uint4*)&Bs[lr][lk]     = *(const uint4*)&Bm[(size_t)(n0+lr)*ldb + k0 + lk];
    *(uint4*)&Bs[lr][lk+8]   = *(const uint4*)&Bm[(size_t)(n0+lr)*ldb + k0 + lk + 8];
    __syncthreads();
    h8 af[4], bf[4];
    #pragma unroll
    for (int r = 0; r < 4; r++) af[r] = *(const h8*)&As[wm + r*16 + frow][kg];
    #pragma unroll
    for (int c = 0; c < 4; c++) bf[c] = *(const h8*)&Bs[wn + c*16 + frow][kg];
    #pragma unroll
    for (int r = 0; r < 4; r++)
      #pragma unroll
      for (int c = 0; c < 4; c++)
        acc[r][c] = __builtin_amdgcn_mfma_f32_16x16x32_f16(af[r], bf[c], acc[r][c], 0, 0, 0);
    __syncthreads();
  }
  int crow = (lane >> 4) * 4, ccol = lane & 15;
  #pragma unroll
  for (int r = 0; r < 4; r++)
    #pragma unroll
    for (int c = 0; c < 4; c++)
      #pragma unroll
      for (int i = 0; i < 4; i++){
        int m = m0 + wm + r*16 + crow + i;
        int n = n0 + wn + c*16 + ccol;
        float v = acc[r][c][i] + bias[n];
        if (mode == 0) ((float*)outp)[(size_t)m*N + n] = v;
        else ((unsigned short*)outp)[(size_t)m*N + n] =
               __builtin_bit_cast(unsigned short, (_Float16)v);
      }
}

// ---------------- phase A: 256 blocks = 32 b x 8 slices, group barriers ------
struct PA {
  const unsigned* Wg; const unsigned* Wq2;
  const float* giE; const float* b_hh;
  const unsigned short* pre2; const unsigned short* mem2;
  const unsigned char* mask;
  const float* v_att; const float* w_cov;
  const float* hb;
  float* hxG; float* tgtG; float* ctxG; float* denomG;
  unsigned* ctr;
  float* energyAll; unsigned short* rinb;
  float* attn_out; float* covh_out;
};

// Fence-free group barrier (r7-proven): release-add drains producer stores to
// the coherence point; consumers use agent-scope atomic loads (L2-bypass).
__device__ __forceinline__ void gbar(unsigned* ctr, unsigned target){
  __syncthreads();
  if (threadIdx.x == 0){
    __hip_atomic_fetch_add(ctr, 1u, __ATOMIC_RELEASE, __HIP_MEMORY_SCOPE_AGENT);
    unsigned v;
    do {
      v = __hip_atomic_load(ctr, __ATOMIC_RELAXED, __HIP_MEMORY_SCOPE_AGENT);
      if (v < target) __builtin_amdgcn_s_sleep(2);
    } while (v < target);
  }
  __syncthreads();
  asm volatile("" ::: "memory");
}

__global__ __launch_bounds__(512, 2) void step_all(PA P){
  const int tid = threadIdx.x;
  const int wv = tid >> 6, l = tid & 63;

  __shared__ __align__(16) u32x4 pre_l4[SB*64];   // 51.2 KB f16
  __shared__ __align__(16) u32x4 mem_l4[SB*64];   // 51.2 KB f16
  __shared__ float ctxw[8*Dz];                    // 16 KB
  __shared__ float tgt_l[Dz];                     // 2 KB
  __shared__ __align__(16) unsigned c2p[8*36];    // ctx f16 pairs, oct-padded
  __shared__ __align__(16) unsigned h2p[8*36];    // h   f16 pairs, oct-padded
  __shared__ unsigned hn2sl[32];                  // h_new slice f16 pairs
  __shared__ float hsl[64];                       // h slice f32
  __shared__ float gi6[192], bh6[192];
  __shared__ float covp[SB], pl[SB], wsum[8], sden[8];
  __shared__ unsigned char mk[SB];
  __shared__ int sjb[2];

  // ---- one-time XCD-aware work assignment: j = physical XCC, b = rank -------
  // Guarantees same-j blocks share an XCD L2 regardless of dispatch mapping.
  // Correctness never depends on the mapping (overflow path is deterministic).
  unsigned* claim = P.ctr + Bz*16;
  if (tid == 0){
    unsigned xcc = __builtin_amdgcn_s_getreg((31u<<11) | 20u) & 7u;  // HW_REG_XCC_ID
    unsigned r = __hip_atomic_fetch_add(&claim[xcc], 1u, __ATOMIC_RELAXED, __HIP_MEMORY_SCOPE_AGENT);
    sjb[0] = (int)xcc; sjb[1] = (int)r;
  }
  gbar(&claim[12], 256);                 // all 256 claims visible
  int b, j;
  {
    int xcc = sjb[0], r = sjb[1];
    if (r < 32){ j = xcc; b = r; }
    else {
      if (tid == 0) sjb[0] = (int)__hip_atomic_fetch_add(&claim[8], 1u, __ATOMIC_RELAXED, __HIP_MEMORY_SCOPE_AGENT);
      __syncthreads();
      int o = sjb[0];
      j = 7; b = 31;
      int cnt = 0;
      for (int k = 0; k < 8; k++){
        int used = aload_i(&claim[k]);
        if (used > 32) used = 32;
        int fr = 32 - used;
        if (o >= cnt && o < cnt + fr){ j = k; b = used + (o - cnt); }
        cnt += fr;
      }
    }
  }
  const int sbase = j * SB;
  unsigned* ctr = P.ctr + b*16;
  unsigned barn = 0;

  // per-lane attention constants
  f32x4 vva = *(const f32x4*)(P.v_att + l*8);
  f32x4 vvb = *(const f32x4*)(P.v_att + l*8 + 4);
  f32x4 wva = *(const f32x4*)(P.w_cov + l*8);
  f32x4 wvb = *(const f32x4*)(P.w_cov + l*8 + 4);

  const u32x4* WgJ4 = (const u32x4*)P.Wg;

  for (int t = 0; t < Tz; t++){
    if (t == 0){
      // ---- init: pre/mem slices into LDS, h, cov, masks, biases, gi[0] ----
      const u32x4* pq = (const u32x4*)P.pre2 + ((size_t)b*Sz + sbase)*64;
      const u32x4* mq = (const u32x4*)P.mem2 + ((size_t)b*Sz + sbase)*64;
      for (int v = tid; v < SB*64; v += 512){ pre_l4[v] = pq[v]; mem_l4[v] = mq[v]; }
      if (tid < 256){
        c2p[(tid>>5)*36 + (tid&31)] = 0u;
        float2 hv = *(const float2*)&P.hb[(size_t)b*Dz + 2*tid];
        h2p[(tid>>5)*36 + (tid&31)] = packh2(hv.x, hv.y);
      }
      if (tid < 64) hsl[tid] = P.hb[(size_t)b*Dz + j*64 + tid];
      if (tid >= 256 && tid < 256+SB){
        int s = tid - 256;
        covp[s] = 0.f;
        mk[s] = P.mask[b*Sz + sbase + s];
        P.covh_out[(size_t)b*Sz + sbase + s] = 0.f;
      }
      if (tid >= 320 && tid < 512){
        int idx = tid - 320;
        bh6[idx] = P.b_hh[(idx>>6)*512 + j*64 + (idx&63)];
        gi6[idx] = P.giE[(size_t)b*G3 + (idx>>6)*512 + j*64 + (idx&63)];
      }
    } else {
      barn++; gbar(ctr, JB*barn);
      // ---- phase X: finalize t-1 ctx/scores ----
      if (tid < 8) sden[tid] = aload_f(&P.denomG[b*8 + tid]);   // den loaded ONCE
      __syncthreads();
      float invd = 1.f/(sden[0]+sden[1]+sden[2]+sden[3]+sden[4]+sden[5]+sden[6]+sden[7]);
      if (tid < 256){
        int p = tid;
        float c0 = 0.f, c1 = 0.f;
        #pragma unroll
        for (int jj = 0; jj < JB; jj++){
          float2 v = aload_f2(&P.ctxG[((size_t)(b*8+jj))*Dz + 2*p]);
          c0 += v.x; c1 += v.y;
        }
        c0 *= invd; c1 *= invd;
        c2p[(p>>5)*36 + (p&31)] = packh2(c0, c1);
        if ((p>>5) == j){
          unsigned* rp = (unsigned*)&P.rinb[((size_t)(t-1)*Bz + b)*G3 + 1024 + 2*p];
          rp[0] = f2bf2(c0, c1);
        }
      } else if (tid < 256+SB){
        int s = tid - 256;
        float sp = pl[s]*invd;
        P.attn_out[((size_t)(t-1)*Bz + b)*Sz + sbase + s] = sp;
        float cc = covp[s] + sp;
        covp[s] = cc;
        P.covh_out[((size_t)t*Bz + b)*Sz + sbase + s] = cc;
      }
    }
    __syncthreads();

    // ---- phase Y: GRU k-slice via f16 dot2 (unroll 4 -> 24 loads in flight) --
    {
      int k3 = tid >> 3, oct = tid & 7;
      float a0=0,a1=0,a2=0,a3=0,a4=0,a5=0;
      const u32x4* c4 = (const u32x4*)c2p + oct*9;
      const u32x4* h4 = (const u32x4*)h2p + oct*9;
      size_t wb = (((size_t)(j*64 + k3)*6)*8 + oct)*8;
      #pragma unroll 4
      for (int i = 0; i < 8; i++){
        u32x4 xc = c4[i];
        u32x4 xh = h4[i];
        u32x4 w0 = WgJ4[wb + i];
        u32x4 w1 = WgJ4[wb + 64 + i];
        u32x4 w2 = WgJ4[wb + 128 + i];
        u32x4 w3 = WgJ4[wb + 192 + i];
        u32x4 w4 = WgJ4[wb + 256 + i];
        u32x4 w5 = WgJ4[wb + 320 + i];
        #pragma unroll
        for (int q = 0; q < 4; q++){
          half2_t xcv = bch2(xc[q]), xhv = bch2(xh[q]);
          a0 = FDOT(bch2(w0[q]), xcv, a0);
          a1 = FDOT(bch2(w1[q]), xcv, a1);
          a2 = FDOT(bch2(w2[q]), xcv, a2);
          a3 = FDOT(bch2(w3[q]), xhv, a3);
          a4 = FDOT(bch2(w4[q]), xhv, a4);
          a5 = FDOT(bch2(w5[q]), xhv, a5);
        }
      }
      a0 += __shfl_xor(a0,1); a0 += __shfl_xor(a0,2); a0 += __shfl_xor(a0,4);
      a1 += __shfl_xor(a1,1); a1 += __shfl_xor(a1,2); a1 += __shfl_xor(a1,4);
      a2 += __shfl_xor(a2,1); a2 += __shfl_xor(a2,2); a2 += __shfl_xor(a2,4);
      a3 += __shfl_xor(a3,1); a3 += __shfl_xor(a3,2); a3 += __shfl_xor(a3,4);
      a4 += __shfl_xor(a4,1); a4 += __shfl_xor(a4,2); a4 += __shfl_xor(a4,4);
      a5 += __shfl_xor(a5,1); a5 += __shfl_xor(a5,2); a5 += __shfl_xor(a5,4);
      if (oct == 0){
        float gir = gi6[k3]     + a0;
        float giz = gi6[64+k3]  + a1;
        float gin = gi6[128+k3] + a2;
        float ghr = bh6[k3]     + a3;
        float ghz = bh6[64+k3]  + a4;
        float ghn = bh6[128+k3] + a5;
        float r = sigm(gir + ghr);
        float z = sigm(giz + ghz);
        float nn = tanhfast(gin + r*ghn);
        float hv = (1.f - z)*nn + z*hsl[k3];
        hsl[k3] = hv;
        astore_f(&P.hxG[(size_t)b*Dz + j*64 + k3], hv);
        P.rinb[((size_t)t*Bz + b)*G3 + 512 + j*64 + k3] = f2bf(hv);
      }
    }
    __syncthreads();
    if (tid < 32) hn2sl[tid] = packh2(hsl[2*tid], hsl[2*tid+1]);
    __syncthreads();
    {
      // tgt partial: 512 outputs x own 64-k slice
      float f = 0.f;
      const unsigned* wq = P.Wq2 + (size_t)j*32*512 + tid;
      #pragma unroll 8
      for (int i = 0; i < 32; i++)
        f = FDOT(bch2(wq[(size_t)i*512]), bch2(hn2sl[i]), f);
      astore_f(&P.tgtG[((size_t)(b*8+j))*Dz + tid], f);
    }
    barn++; gbar(ctr, JB*barn);

    // ---- phase Z: gather h/tgt (vectorized atomics); attention on LDS rows --
    if (tid < 256){
      int p = tid;
      float t0 = 0.f, t1 = 0.f;
      #pragma unroll
      for (int jj = 0; jj < JB; jj++){
        float2 v = aload_f2(&P.tgtG[((size_t)(b*8+jj))*Dz + 2*p]);
        t0 += v.x; t1 += v.y;
      }
      tgt_l[2*p] = t0; tgt_l[2*p+1] = t1;
    } else {
      int p = tid - 256;
      float2 hv = aload_f2(&P.hxG[(size_t)b*Dz + 2*p]);
      h2p[(p>>5)*36 + (p&31)] = packh2(hv.x, hv.y);
    }
    __syncthreads();
    {
      f32x4 t8a = *(const f32x4*)&tgt_l[l*8];
      f32x4 t8b = *(const f32x4*)&tgt_l[l*8 + 4];
      f32x4 ca = (f32x4){0.f,0.f,0.f,0.f}, cb = ca;
      float dsum = 0.f;
      #pragma unroll
      for (int i = 0; i < 7; i++){
        int s = wv + 8*i;
        if (s < SB){
          float cv = covp[s];
          int mkk = mk[s];
          u32x4 pq = pre_l4[s*64 + l];
          f32x4 ba = t8a + cv*wva, bb = t8b + cv*wvb;
          half2_t h0=bch2(pq[0]), h1=bch2(pq[1]), h2v=bch2(pq[2]), h3=bch2(pq[3]);
          float acc;
          acc  = vva[0]*tanhfast((float)h0[0] + ba[0]);
          acc += vva[1]*tanhfast((float)h0[1] + ba[1]);
          acc += vva[2]*tanhfast((float)h1[0] + ba[2]);
          acc += vva[3]*tanhfast((float)h1[1] + ba[3]);
          acc += vvb[0]*tanhfast((float)h2v[0] + bb[0]);
          acc += vvb[1]*tanhfast((float)h2v[1] + bb[1]);
          acc += vvb[2]*tanhfast((float)h3[0] + bb[2]);
          acc += vvb[3]*tanhfast((float)h3[1] + bb[3]);
          #pragma unroll
          for (int m = 1; m < 64; m <<= 1) acc += __shfl_xor(acc, m);
          float en = mkk ? -NEGC : acc;
          float p = __expf(en);
          if (l == 0){
            P.energyAll[((size_t)t*Bz + b)*Sz + sbase + s] = en;
            pl[s] = p;
            dsum += p;
          }
          u32x4 mq = mem_l4[s*64 + l];
          half2_t m0=bch2(mq[0]), m1=bch2(mq[1]), m2=bch2(mq[2]), m3=bch2(mq[3]);
          ca[0] += p*(float)m0[0]; ca[1] += p*(float)m0[1];
          ca[2] += p*(float)m1[0]; ca[3] += p*(float)m1[1];
          cb[0] += p*(float)m2[0]; cb[1] += p*(float)m2[1];
          cb[2] += p*(float)m3[0]; cb[3] += p*(float)m3[1];
        }
      }
      if (l == 0) wsum[wv] = dsum;
      *(f32x4*)&ctxw[wv*Dz + l*8]     = ca;
      *(f32x4*)&ctxw[wv*Dz + l*8 + 4] = cb;
    }
    __syncthreads();
    {
      float cs = 0.f;
      #pragma unroll
      for (int w = 0; w < 8; w++) cs += ctxw[w*Dz + tid];
      astore_f(&P.ctxG[((size_t)(b*8+j))*Dz + tid], cs);
    }
    if (tid == 0){
      float ds = 0.f;
      #pragma unroll
      for (int w = 0; w < 8; w++) ds += wsum[w];
      astore_f(&P.denomG[b*8 + j], ds);
    }
    // prefetch gi[t+1] into LDS (overlaps ctx stores; consumed after next gbar)
    if (t+1 < Tz && tid >= 320){
      int idx = tid - 320;
      gi6[idx] = P.giE[((size_t)(t+1)*Bz + b)*G3 + (idx>>6)*512 + j*64 + (idx&63)];
    }
  }

  // ---- drain: t=63 scores + ctx ----
  barn++; gbar(ctr, JB*barn);
  {
    float den = 0.f;
    #pragma unroll
    for (int jj = 0; jj < JB; jj++) den += aload_f(&P.denomG[b*8 + jj]);
    float invd = 1.f/den;
    if (tid < 256){
      int p = tid;
      if ((p>>5) == j){
        float c0 = 0.f, c1 = 0.f;
        #pragma unroll
        for (int jj = 0; jj < JB; jj++){
          float2 v = aload_f2(&P.ctxG[((size_t)(b*8+jj))*Dz + 2*p]);
          c0 += v.x; c1 += v.y;
        }
        unsigned* rp = (unsigned*)&P.rinb[((size_t)63*Bz + b)*G3 + 1024 + 2*p];
        rp[0] = f2bf2(c0*invd, c1*invd);
      }
    } else if (tid < 256+SB){
      int s = tid - 256;
      P.attn_out[((size_t)63*Bz + b)*Sz + sbase + s] = pl[s]*invd;
    }
  }
}

// ---------------- maxout + cast ---------------------------------------------
__global__ __launch_bounds__(256) void maxout_k(const float* __restrict__ rout,
    unsigned short* __restrict__ mo){
  int m = blockIdx.x, d = threadIdx.x;
  float a = rout[(size_t)m*Dz + 2*d], b = rout[(size_t)m*Dz + 2*d + 1];
  mo[(size_t)m*256 + d] = f2bf(fmaxf(a, b));
}

// ---------------- OOV fill ---------------------------------------------------
__global__ __launch_bounds__(64) void oov_fill(float* __restrict__ out, int Vext){
  int m = blockIdx.x;
  int b = m & 31, t = m >> 5;
  size_t base = (size_t)(b*Tz + t) * Vext;
  for (int v = VOC + threadIdx.x; v < Vext; v += 64)
    out[base + v] = -NEGC;
}

// ---------------- pointer scatter -------------------------------------------
__global__ __launch_bounds__(256) void scatter_k(const int* __restrict__ ext,
    const float* __restrict__ energyAll, float* __restrict__ out, int Vext){
  __shared__ int ex[Sz];
  __shared__ float en[Sz];
  int m = blockIdx.x;
  int t = m >> 5, b = m & 31;
  int tid = threadIdx.x;
  for (int s = tid; s < Sz; s += 256){
    ex[s] = ext[b*Sz + s];
    en[s] = energyAll[(size_t)m*Sz + s];
  }
  __syncthreads();
  size_t base = (size_t)(b*Tz + t) * Vext;
  for (int s = tid; s < Sz; s += 256){
    int v = ex[s];
    float mv = -3.4e38f; int idx = -1;
    for (int s2 = 0; s2 < Sz; s2++){
      if (ex[s2] == v && en[s2] > mv){ mv = en[s2]; idx = s2; }
    }
    if (idx == s && mv != -NEGC){
      if (v < VOC){
        float w = out[base + v] + mv;
        out[base + v] = (w == 0.f) ? -NEGC : w;
      } else {
        out[base + v] = (mv == 0.f) ? -NEGC : mv;
      }
    }
  }
}

// ============================================================================
extern "C" void kernel_launch(void* const* d_in, const int* in_sizes, int n_in,
                              void* d_out, int out_size, void* d_ws, size_t ws_size,
                              hipStream_t stream){
  const float* emb     = (const float*)d_in[0];
  const float* enc0    = (const float*)d_in[1];
  const float* mem     = (const float*)d_in[2];
  const float* W_trans = (const float*)d_in[3];
  const float* b_trans = (const float*)d_in[4];
  const float* W_ih    = (const float*)d_in[5];
  const float* W_hh    = (const float*)d_in[6];
  const float* b_ih    = (const float*)d_in[7];
  const float* b_hh    = (const float*)d_in[8];
  const float* W_pre   = (const float*)d_in[9];
  const float* b_pre   = (const float*)d_in[10];
  const float* W_q     = (const float*)d_in[11];
  const float* W_cov   = (const float*)d_in[12];
  const float* v_att   = (const float*)d_in[13];
  const float* W_ro    = (const float*)d_in[14];
  const float* b_ro    = (const float*)d_in[15];
  const float* W_logit = (const float*)d_in[16];
  const float* b_logit = (const float*)d_in[17];
  const int*   ext     = (const int*)d_in[18];
  const unsigned char* maskp = (const unsigned char*)d_in[19];
  float* out = (float*)d_out;

  const int Vext = (out_size - 2*Tz*Bz*Sz) / (Bz*Tz);

  char* ws = (char*)d_ws;
  size_t off = 0;
  auto alloc = [&](size_t bytes)->void*{
    void* p = ws + off;
    off += (bytes + 255) & ~(size_t)255;
    return p;
  };
  float* giE         = (float*)alloc((size_t)Tz*Bz*G3*4);
  unsigned* Wg       = (unsigned*)alloc((size_t)786432*4);
  unsigned* Wq2      = (unsigned*)alloc((size_t)131072*4);
  unsigned short* pre2 = (unsigned short*)alloc((size_t)Bz*Sz*Dz*2);
  unsigned short* mem2 = (unsigned short*)alloc((size_t)Bz*Sz*Dz*2);
  unsigned short* emb2 = (unsigned short*)alloc((size_t)Tz*Bz*Dz*2);
  unsigned short* Wih2 = (unsigned short*)alloc((size_t)G3*Dz*2);
  unsigned short* Wpre2= (unsigned short*)alloc((size_t)Dz*Dz*2);
  float* hb          = (float*)alloc((size_t)Bz*Dz*4);
  float* hxG         = (float*)alloc((size_t)Bz*Dz*4);
  float* tgtG        = (float*)alloc((size_t)Bz*JB*Dz*4);
  float* ctxG        = (float*)alloc((size_t)Bz*JB*Dz*4);
  float* denomG      = (float*)alloc((size_t)Bz*JB*4);
  unsigned* ctr      = (unsigned*)alloc((size_t)(Bz*16 + 16)*4);
  float* energyAll   = (float*)alloc((size_t)Tz*Bz*Sz*4);
  float* rout        = (float*)alloc((size_t)Tz*Bz*Dz*4);
  unsigned short* rin_bf = (unsigned short*)alloc((size_t)Tz*Bz*G3*2);
  unsigned short* Wro_bf = (unsigned short*)alloc((size_t)Dz*G3*2);
  unsigned short* mo_bf  = (unsigned short*)alloc((size_t)Tz*Bz*256*2);
  unsigned short* Wl_bf  = (unsigned short*)alloc((size_t)VOC*256*2);

  float* attn_out = out + (size_t)Bz*Tz*Vext;
  float* covh_out = attn_out + (size_t)Tz*Bz*Sz;

  // -------- phase 0: precompute --------
  repack_emb<<<Tz*Bz, 128, 0, stream>>>(emb, emb2, rin_bf);
  wgj_pack<<<3072, 256, 0, stream>>>(W_ih, W_hh, Wg);
  wq2_pack<<<512, 256, 0, stream>>>(W_q, Wq2);
  zero_u32<<<3, 256, 0, stream>>>(ctr, Bz*16 + 16);
  cast_f16<<<2048, 256, 0, stream>>>(mem, mem2, Bz*Sz*Dz);
  cast_f16_str<<<1024, 256, 0, stream>>>(W_ih, 1024, Wih2, 512, G3*Dz);
  cast_f16<<<512, 256, 0, stream>>>(W_pre, (unsigned short*)Wpre2, Dz*Dz);
  gemm_f32<<<dim3(1, Dz/64), 256, 0, stream>>>(enc0, Dz, W_trans, Dz, b_trans, hb, Dz, Bz, Dz, Dz);
  mfma_f16k<<<dim3(Tz*Bz/128, G3/128), 256, 0, stream>>>(emb2, Dz, Wih2, Dz, b_ih,
                                                         giE, G3, Dz, 0);
  mfma_f16k<<<dim3(Bz*Sz/128, Dz/128), 256, 0, stream>>>(mem2, Dz, Wpre2, Dz, b_pre,
                                                         pre2, Dz, Dz, 2);
  cast_bf<<<1024, 256, 0, stream>>>(W_ro, Wro_bf, Dz*G3);
  cast_bf<<<2048, 256, 0, stream>>>(W_logit, Wl_bf, VOC*256);

  // -------- phase A: 256-block cooperative kernel, XCD-claimed (b,j) ---------
  PA P;
  P.Wg = Wg; P.Wq2 = Wq2; P.giE = giE; P.b_hh = b_hh;
  P.pre2 = pre2; P.mem2 = mem2; P.mask = maskp; P.v_att = v_att; P.w_cov = W_cov;
  P.hb = hb; P.hxG = hxG; P.tgtG = tgtG; P.ctxG = ctxG; P.denomG = denomG;
  P.ctr = ctr; P.energyAll = energyAll; P.rinb = rin_bf;
  P.attn_out = attn_out; P.covh_out = covh_out;
  void* kargs[] = { (void*)&P };
  hipLaunchCooperativeKernel((void*)step_all, dim3(Bz*JB), dim3(512), kargs, 0, stream);

  // -------- phase B: batched readout -> maxout -> logits -> pointer --------
  mfma_bf16<<<dim3(Tz*Bz/128, Dz/128), 256, 0, stream>>>(rin_bf, G3, Wro_bf, G3, b_ro,
                                                         rout, Dz, G3, 0, 0);
  maxout_k<<<Tz*Bz, 256, 0, stream>>>(rout, mo_bf);
  mfma_bf16<<<dim3(Tz*Bz/128, VOC/128), 256, 0, stream>>>(mo_bf, 256, Wl_bf, 256, b_logit,
                                                          out, VOC, 256, 1, Vext);
  oov_fill<<<Tz*Bz, 64, 0, stream>>>(out, Vext);
  scatter_k<<<Tz*Bz, 256, 0, stream>>>(ext, energyAll, out, Vext);
  (void)in_sizes; (void)n_in; (void)ws_size;
}

// Round 13
// 2132.056 us; speedup vs baseline: 1.0465x; 1.0465x over previous
//
#include <hip/hip_runtime.h>

#define Bz 32
#define Tz 64
#define Sz 400
#define Dz 512
#define G3 1536
#define VOC 32000
#define NEGC 1e12f
#define SB 50          // s-rows per block
#define JB 8           // blocks per batch element

typedef __attribute__((ext_vector_type(8))) short short8;
typedef __attribute__((ext_vector_type(8))) _Float16 h8;
typedef __attribute__((ext_vector_type(4))) float f32x4;
typedef __attribute__((ext_vector_type(4))) unsigned u32x4;
typedef __attribute__((ext_vector_type(2))) _Float16 half2_t;

__device__ __forceinline__ float sigm(float x){ return 1.f/(1.f+__expf(-x)); }
__device__ __forceinline__ float tanhfast(float x){ float e=__expf(2.f*x); return 1.f - 2.f/(e+1.f); }
__device__ __forceinline__ unsigned short f2bf(float f){
  unsigned int u = __float_as_uint(f);
  u = (u + 0x7FFFu + ((u>>16)&1u)) >> 16;
  return (unsigned short)u;
}
__device__ __forceinline__ unsigned f2bf2(float a, float b){
  return (unsigned)f2bf(a) | ((unsigned)f2bf(b) << 16);
}
__device__ __forceinline__ half2_t bch2(unsigned u){ return __builtin_bit_cast(half2_t, u); }
__device__ __forceinline__ unsigned packh2(float a, float b){
  unsigned short ua = __builtin_bit_cast(unsigned short, (_Float16)a);
  unsigned short ub = __builtin_bit_cast(unsigned short, (_Float16)b);
  return (unsigned)ua | ((unsigned)ub << 16);
}

// ---- agent-scope coherent accessors (bypass stale L2 on BOTH sides; r7-proven
// correct under harness poison+replay — plain consumer loads are NOT safe)
__device__ __forceinline__ float aload_f(const float* p){
  unsigned v = __hip_atomic_load((unsigned*)p, __ATOMIC_RELAXED, __HIP_MEMORY_SCOPE_AGENT);
  return __uint_as_float(v);
}
__device__ __forceinline__ unsigned long long aload_u64(const void* p){
  return __hip_atomic_load((const unsigned long long*)p, __ATOMIC_RELAXED, __HIP_MEMORY_SCOPE_AGENT);
}
__device__ __forceinline__ void astore_f(float* p, float v){
  __hip_atomic_store((unsigned*)p, __float_as_uint(v), __ATOMIC_RELAXED, __HIP_MEMORY_SCOPE_AGENT);
}
__device__ __forceinline__ void astore_u32(unsigned* p, unsigned v){
  __hip_atomic_store(p, v, __ATOMIC_RELAXED, __HIP_MEMORY_SCOPE_AGENT);
}

#if defined(__has_builtin)
#if __has_builtin(__builtin_amdgcn_fdot2)
#define HAVE_FDOT2 1
#endif
#endif
#ifdef HAVE_FDOT2
__device__ __forceinline__ float FDOT(half2_t a, half2_t b, float c){
  return __builtin_amdgcn_fdot2(a, b, c, false);
}
#else
__device__ __forceinline__ float FDOT(half2_t a, half2_t b, float c){
  return c + (float)a[0]*(float)b[0] + (float)a[1]*(float)b[1];
}
#endif

// ---------------- repack emb: (b,t,e) -> emb2 f16 (t*B+b,e) + rin_bf bf16 ----
__global__ __launch_bounds__(128) void repack_emb(const float* __restrict__ emb,
    unsigned short* __restrict__ emb2, unsigned short* __restrict__ rinb){
  int tb = blockIdx.x; int t = tb >> 5, b = tb & 31;
  int e4 = threadIdx.x;
  float4 v = *(const float4*)&emb[((size_t)b*Tz + t)*Dz + e4*4];
  unsigned* e2 = (unsigned*)&emb2[(size_t)tb*Dz + e4*4];
  e2[0] = packh2(v.x, v.y);
  e2[1] = packh2(v.z, v.w);
  unsigned* rb = (unsigned*)&rinb[(size_t)tb*G3 + e4*4];
  rb[0] = f2bf2(v.x, v.y);
  rb[1] = f2bf2(v.z, v.w);
}

// ---- GRU weights, k-slice layout: Wg[((k*6+s)*8+oct)*32 + i] = f16x2 of e=(oct*32+i)*2
__global__ __launch_bounds__(256) void wgj_pack(const float* __restrict__ W_ih,
    const float* __restrict__ W_hh, unsigned* __restrict__ Wg){
  int idx = blockIdx.x*256 + threadIdx.x;   // 512*6*256 = 786432
  int i = idx & 31, oct = (idx>>5)&7;
  int ks = idx >> 8;
  int s = ks % 6, k = ks / 6;
  int e0 = (oct*32 + i)*2;
  float w0, w1;
  if (s < 3){
    const float* base = W_ih + ((size_t)(s*512 + k))*1024 + 512;
    w0 = base[e0]; w1 = base[e0+1];
  } else {
    const float* base = W_hh + ((size_t)((s-3)*512 + k))*512;
    w0 = base[e0]; w1 = base[e0+1];
  }
  Wg[idx] = packh2(w0, w1);
}

// ---- W_q slice layout (JB=8): Wq2[(js*32+i)*512 + jj] = f16x2 of W_q[jj][js*64+2i ..+1]
__global__ __launch_bounds__(256) void wq2_pack(const float* __restrict__ W_q,
    unsigned* __restrict__ Wq2){
  int idx = blockIdx.x*256 + threadIdx.x;   // 131072
  int jj = idx & 511;
  int i  = (idx>>9) & 31;
  int js = idx >> 14;
  int k0 = js*64 + 2*i;
  Wq2[idx] = packh2(W_q[(size_t)jj*512 + k0], W_q[(size_t)jj*512 + k0 + 1]);
}

__global__ __launch_bounds__(256) void cast_f16(const float* __restrict__ in,
    unsigned short* __restrict__ out, int n){
  for (int i = blockIdx.x*256 + threadIdx.x; i < n; i += gridDim.x*256)
    out[i] = __builtin_bit_cast(unsigned short, (_Float16)in[i]);
}

// strided f16 cast: out[r*cols+c] = f16(in[r*ldi + c])
__global__ __launch_bounds__(256) void cast_f16_str(const float* __restrict__ in, int ldi,
    unsigned short* __restrict__ out, int cols, int n){
  for (int i = blockIdx.x*256 + threadIdx.x; i < n; i += gridDim.x*256){
    int r = i / cols, c = i - r*cols;
    out[i] = __builtin_bit_cast(unsigned short, (_Float16)in[(size_t)r*ldi + c]);
  }
}

__global__ __launch_bounds__(256) void cast_bf(const float* __restrict__ in,
    unsigned short* __restrict__ out, int n){
  for (int i = blockIdx.x*256 + threadIdx.x; i < n; i += gridDim.x*256)
    out[i] = f2bf(in[i]);
}

__global__ __launch_bounds__(256) void zero_u32(unsigned* __restrict__ p, int n){
  int i = blockIdx.x*256 + threadIdx.x;
  if (i < n) p[i] = 0u;
}

// ---------------- f32 tiled GEMM (only tiny h0 uses it now) ------------------
__global__ __launch_bounds__(256) void gemm_f32(const float* __restrict__ A, int lda,
    const float* __restrict__ Bm, int ldb, const float* __restrict__ bias,
    float* __restrict__ C, int ldc, int M, int N, int K){
  __shared__ __align__(16) float As[16][68];
  __shared__ __align__(16) float Bs[16][68];
  int tid = threadIdx.x;
  int m0 = blockIdx.x * 64, n0 = blockIdx.y * 64;
  int tx = tid & 15, ty = tid >> 4;
  float acc[4][4] = {};
  int lr = tid >> 2;
  int lk = (tid & 3) << 2;
  for (int k0 = 0; k0 < K; k0 += 16){
    int m = m0 + lr;
    float4 va = (m < M) ? *(const float4*)&A[(size_t)m*lda + k0 + lk] : make_float4(0,0,0,0);
    int n = n0 + lr;
    float4 vb = (n < N) ? *(const float4*)&Bm[(size_t)n*ldb + k0 + lk] : make_float4(0,0,0,0);
    As[lk+0][lr]=va.x; As[lk+1][lr]=va.y; As[lk+2][lr]=va.z; As[lk+3][lr]=va.w;
    Bs[lk+0][lr]=vb.x; Bs[lk+1][lr]=vb.y; Bs[lk+2][lr]=vb.z; Bs[lk+3][lr]=vb.w;
    __syncthreads();
    #pragma unroll
    for (int kk = 0; kk < 16; kk++){
      float4 a = *(const float4*)&As[kk][ty*4];
      float4 b = *(const float4*)&Bs[kk][tx*4];
      float av[4] = {a.x,a.y,a.z,a.w};
      float bv[4] = {b.x,b.y,b.z,b.w};
      #pragma unroll
      for (int i = 0; i < 4; i++)
        #pragma unroll
        for (int j = 0; j < 4; j++)
          acc[i][j] += av[i]*bv[j];
    }
    __syncthreads();
  }
  #pragma unroll
  for (int i = 0; i < 4; i++){
    int m = m0 + ty*4 + i;
    if (m >= M) continue;
    #pragma unroll
    for (int j = 0; j < 4; j++){
      int n = n0 + tx*4 + j;
      if (n < N) C[(size_t)m*ldc + n] = acc[i][j] + bias[n];
    }
  }
}

// ---------------- bf16 MFMA GEMM: out = A_bf @ B_bf^T + bias ----------------
__global__ __launch_bounds__(256) void mfma_bf16(const unsigned short* __restrict__ A, int lda,
    const unsigned short* __restrict__ Bm, int ldb, const float* __restrict__ bias,
    float* __restrict__ out, int N, int K, int mode, int Vext){
  __shared__ __align__(16) unsigned short As[128][40];
  __shared__ __align__(16) unsigned short Bs[128][40];
  int tid = threadIdx.x;
  int m0 = blockIdx.x * 128, n0 = blockIdx.y * 128;
  int wid = tid >> 6, lane = tid & 63;
  int wm = (wid >> 1) * 64, wn = (wid & 1) * 64;
  f32x4 acc[4][4];
  #pragma unroll
  for (int r = 0; r < 4; r++)
    #pragma unroll
    for (int c = 0; c < 4; c++) acc[r][c] = (f32x4){0.f,0.f,0.f,0.f};
  int lr = tid >> 1;
  int lk = (tid & 1) * 16;
  int frow = lane & 15, kg = (lane >> 4) * 8;
  for (int k0 = 0; k0 < K; k0 += 32){
    *(uint4*)&As[lr][lk]     = *(const uint4*)&A[(size_t)(m0+lr)*lda + k0 + lk];
    *(uint4*)&As[lr][lk+8]   = *(const uint4*)&A[(size_t)(m0+lr)*lda + k0 + lk + 8];
    *(uint4*)&Bs[lr][lk]     = *(const uint4*)&Bm[(size_t)(n0+lr)*ldb + k0 + lk];
    *(uint4*)&Bs[lr][lk+8]   = *(const uint4*)&Bm[(size_t)(n0+lr)*ldb + k0 + lk + 8];
    __syncthreads();
    short8 af[4], bf[4];
    #pragma unroll
    for (int r = 0; r < 4; r++) af[r] = *(const short8*)&As[wm + r*16 + frow][kg];
    #pragma unroll
    for (int c = 0; c < 4; c++) bf[c] = *(const short8*)&Bs[wn + c*16 + frow][kg];
    #pragma unroll
    for (int r = 0; r < 4; r++)
      #pragma unroll
      for (int c = 0; c < 4; c++)
        acc[r][c] = __builtin_amdgcn_mfma_f32_16x16x32_bf16(af[r], bf[c], acc[r][c], 0, 0, 0);
    __syncthreads();
  }
  int crow = (lane >> 4) * 4, ccol = lane & 15;
  #pragma unroll
  for (int r = 0; r < 4; r++)
    #pragma unroll
    for (int c = 0; c < 4; c++)
      #pragma unroll
      for (int i = 0; i < 4; i++){
        int m = m0 + wm + r*16 + crow + i;
        int n = n0 + wn + c*16 + ccol;
        float v = acc[r][c][i] + bias[n];
        if (mode == 0){
          out[(size_t)m*N + n] = v;
        } else {
          int b = m & 31, t = m >> 5;
          v = (v == 0.f) ? -NEGC : v;
          out[((size_t)(b*Tz + t))*Vext + n] = v;
        }
      }
}

// ---------------- f16 MFMA GEMM: out = A_h @ B_h^T + bias -------------------
// mode 0: f32 out; mode 2: f16 (u16) out
__global__ __launch_bounds__(256) void mfma_f16k(const unsigned short* __restrict__ A, int lda,
    const unsigned short* __restrict__ Bm, int ldb, const float* __restrict__ bias,
    void* __restrict__ outp, int N, int K, int mode){
  __shared__ __align__(16) unsigned short As[128][40];
  __shared__ __align__(16) unsigned short Bs[128][40];
  int tid = threadIdx.x;
  int m0 = blockIdx.x * 128, n0 = blockIdx.y * 128;
  int wid = tid >> 6, lane = tid & 63;
  int wm = (wid >> 1) * 64, wn = (wid & 1) * 64;
  f32x4 acc[4][4];
  #pragma unroll
  for (int r = 0; r < 4; r++)
    #pragma unroll
    for (int c = 0; c < 4; c++) acc[r][c] = (f32x4){0.f,0.f,0.f,0.f};
  int lr = tid >> 1;
  int lk = (tid & 1) * 16;
  int frow = lane & 15, kg = (lane >> 4) * 8;
  for (int k0 = 0; k0 < K; k0 += 32){
    *(uint4*)&As[lr][lk]     = *(const uint4*)&A[(size_t)(m0+lr)*lda + k0 + lk];
    *(uint4*)&As[lr][lk+8]   = *(const uint4*)&A[(size_t)(m0+lr)*lda + k0 + lk + 8];
    *(uint4*)&Bs[lr][lk]     = *(const uint4*)&Bm[(size_t)(n0+lr)*ldb + k0 + lk];
    *(uint4*)&Bs[lr][lk+8]   = *(const uint4*)&Bm[(size_t)(n0+lr)*ldb + k0 + lk + 8];
    __syncthreads();
    h8 af[4], bf[4];
    #pragma unroll
    for (int r = 0; r < 4; r++) af[r] = *(const h8*)&As[wm + r*16 + frow][kg];
    #pragma unroll
    for (int c = 0; c < 4; c++) bf[c] = *(const h8*)&Bs[wn + c*16 + frow][kg];
    #pragma unroll
    for (int r = 0; r < 4; r++)
      #pragma unroll
      for (int c = 0; c < 4; c++)
        acc[r][c] = __builtin_amdgcn_mfma_f32_16x16x32_f16(af[r], bf[c], acc[r][c], 0, 0, 0);
    __syncthreads();
  }
  int crow = (lane >> 4) * 4, ccol = lane & 15;
  #pragma unroll
  for (int r = 0; r < 4; r++)
    #pragma unroll
    for (int c = 0; c < 4; c++)
      #pragma unroll
      for (int i = 0; i < 4; i++){
        int m = m0 + wm + r*16 + crow + i;
        int n = n0 + wn + c*16 + ccol;
        float v = acc[r][c][i] + bias[n];
        if (mode == 0) ((float*)outp)[(size_t)m*N + n] = v;
        else ((unsigned short*)outp)[(size_t)m*N + n] =
               __builtin_bit_cast(unsigned short, (_Float16)v);
      }
}

// ---------------- phase A: 256 blocks = 32 b x 8 slices, group barriers ------
// Exchange buffers are packed f16 pairs (u32); ctx partials are pre-normalized
// by the producing block's local denominator (bounded by max|mem| -> f16-safe);
// consumer reconstructs ctx = sum_j (den_j/den_tot) * ctx16_j  (exact modulo f16).
struct PA {
  const unsigned* Wg; const unsigned* Wq2;
  const float* giE; const float* b_hh;
  const unsigned short* pre2; const unsigned short* mem2;
  const unsigned char* mask;
  const float* v_att; const float* w_cov;
  const float* hb;
  unsigned* hxG; unsigned* tgtG; unsigned* ctxG; float* denomG;
  unsigned* ctr;
  float* energyAll; unsigned short* rinb;
  float* attn_out; float* covh_out;
};

// Fence-free group barrier (r7-proven): release-add drains producer stores to
// the coherence point; consumers use agent-scope atomic loads (L2-bypass).
__device__ __forceinline__ void gbar(unsigned* ctr, unsigned target){
  __syncthreads();
  if (threadIdx.x == 0){
    __hip_atomic_fetch_add(ctr, 1u, __ATOMIC_RELEASE, __HIP_MEMORY_SCOPE_AGENT);
    unsigned v;
    do {
      v = __hip_atomic_load(ctr, __ATOMIC_RELAXED, __HIP_MEMORY_SCOPE_AGENT);
      if (v < target) __builtin_amdgcn_s_sleep(2);
    } while (v < target);
  }
  __syncthreads();
  asm volatile("" ::: "memory");
}

__global__ __launch_bounds__(512, 2) void step_all(PA P){
  const int bid = blockIdx.x, tid = threadIdx.x;
  const int b = bid >> 3, j = bid & 7;
  const int sbase = j * SB;
  const int wv = tid >> 6, l = tid & 63;

  __shared__ __align__(16) u32x4 pre_l4[SB*64];   // 51.2 KB f16
  __shared__ __align__(16) u32x4 mem_l4[SB*64];   // 51.2 KB f16
  __shared__ float ctxw[8*Dz];                    // 16 KB
  __shared__ float tgt_l[Dz];                     // 2 KB
  __shared__ __align__(16) unsigned c2p[8*36];    // ctx f16 pairs, oct-padded
  __shared__ __align__(16) unsigned h2p[8*36];    // h   f16 pairs, oct-padded
  __shared__ unsigned hn2sl[32];                  // h_new slice f16 pairs
  __shared__ float hsl[64];                       // h slice f32
  __shared__ float gi6[192], bh6[192];
  __shared__ float covp[SB], pl[SB], wsum[8], sden[8];
  __shared__ unsigned char mk[SB];

  unsigned* ctr = P.ctr + b*16;
  unsigned barn = 0;

  // per-lane attention constants
  f32x4 vva = *(const f32x4*)(P.v_att + l*8);
  f32x4 vvb = *(const f32x4*)(P.v_att + l*8 + 4);
  f32x4 wva = *(const f32x4*)(P.w_cov + l*8);
  f32x4 wvb = *(const f32x4*)(P.w_cov + l*8 + 4);

  const u32x4* WgJ4 = (const u32x4*)P.Wg;

  for (int t = 0; t < Tz; t++){
    if (t == 0){
      // ---- init: pre/mem slices into LDS, h, cov, masks, biases, gi[0] ----
      const u32x4* pq = (const u32x4*)P.pre2 + ((size_t)b*Sz + sbase)*64;
      const u32x4* mq = (const u32x4*)P.mem2 + ((size_t)b*Sz + sbase)*64;
      for (int v = tid; v < SB*64; v += 512){ pre_l4[v] = pq[v]; mem_l4[v] = mq[v]; }
      if (tid < 256){
        c2p[(tid>>5)*36 + (tid&31)] = 0u;
        float2 hv = *(const float2*)&P.hb[(size_t)b*Dz + 2*tid];
        h2p[(tid>>5)*36 + (tid&31)] = packh2(hv.x, hv.y);
      }
      if (tid < 64) hsl[tid] = P.hb[(size_t)b*Dz + j*64 + tid];
      if (tid >= 256 && tid < 256+SB){
        int s = tid - 256;
        covp[s] = 0.f;
        mk[s] = P.mask[b*Sz + sbase + s];
        P.covh_out[(size_t)b*Sz + sbase + s] = 0.f;
      }
      if (tid >= 320 && tid < 512){
        int idx = tid - 320;
        bh6[idx] = P.b_hh[(idx>>6)*512 + j*64 + (idx&63)];
        gi6[idx] = P.giE[(size_t)b*G3 + (idx>>6)*512 + j*64 + (idx&63)];
      }
    } else {
      barn++; gbar(ctr, JB*barn);
      // ---- phase X: finalize t-1 ctx/scores (weighted f16 gather) ----
      if (tid < 8) sden[tid] = aload_f(&P.denomG[b*8 + tid]);
      __syncthreads();
      float invd = 1.f/(sden[0]+sden[1]+sden[2]+sden[3]+sden[4]+sden[5]+sden[6]+sden[7]);
      if (tid < 128){
        // e-quad q = tid: e = 4q .. 4q+3 ; u64 carries pairs 2q, 2q+1
        float c0=0.f, c1=0.f, c2=0.f, c3=0.f;
        #pragma unroll
        for (int jj = 0; jj < JB; jj++){
          unsigned long long v = aload_u64(&P.ctxG[((size_t)(b*8+jj))*256 + 2*tid]);
          float w = sden[jj];
          half2_t p0 = bch2((unsigned)v), p1 = bch2((unsigned)(v >> 32));
          c0 += w*(float)p0[0]; c1 += w*(float)p0[1];
          c2 += w*(float)p1[0]; c3 += w*(float)p1[1];
        }
        c0 *= invd; c1 *= invd; c2 *= invd; c3 *= invd;
        int p0i = 2*tid, p1i = 2*tid + 1;
        c2p[(p0i>>5)*36 + (p0i&31)] = packh2(c0, c1);
        c2p[(p1i>>5)*36 + (p1i&31)] = packh2(c2, c3);
        if ((tid >> 4) == j){
          unsigned* rp = (unsigned*)&P.rinb[((size_t)(t-1)*Bz + b)*G3 + 1024 + 4*tid];
          rp[0] = f2bf2(c0, c1); rp[1] = f2bf2(c2, c3);
        }
      } else if (tid >= 256 && tid < 256+SB){
        int s = tid - 256;
        float sp = pl[s]*invd;
        P.attn_out[((size_t)(t-1)*Bz + b)*Sz + sbase + s] = sp;
        float cc = covp[s] + sp;
        covp[s] = cc;
        P.covh_out[((size_t)t*Bz + b)*Sz + sbase + s] = cc;
      }
    }
    __syncthreads();

    // ---- phase Y: GRU k-slice via f16 dot2 (unroll 4 -> 24 loads in flight) --
    {
      int k3 = tid >> 3, oct = tid & 7;
      float a0=0,a1=0,a2=0,a3=0,a4=0,a5=0;
      const u32x4* c4 = (const u32x4*)c2p + oct*9;
      const u32x4* h4 = (const u32x4*)h2p + oct*9;
      size_t wb = (((size_t)(j*64 + k3)*6)*8 + oct)*8;
      #pragma unroll 4
      for (int i = 0; i < 8; i++){
        u32x4 xc = c4[i];
        u32x4 xh = h4[i];
        u32x4 w0 = WgJ4[wb + i];
        u32x4 w1 = WgJ4[wb + 64 + i];
        u32x4 w2 = WgJ4[wb + 128 + i];
        u32x4 w3 = WgJ4[wb + 192 + i];
        u32x4 w4 = WgJ4[wb + 256 + i];
        u32x4 w5 = WgJ4[wb + 320 + i];
        #pragma unroll
        for (int q = 0; q < 4; q++){
          half2_t xcv = bch2(xc[q]), xhv = bch2(xh[q]);
          a0 = FDOT(bch2(w0[q]), xcv, a0);
          a1 = FDOT(bch2(w1[q]), xcv, a1);
          a2 = FDOT(bch2(w2[q]), xcv, a2);
          a3 = FDOT(bch2(w3[q]), xhv, a3);
          a4 = FDOT(bch2(w4[q]), xhv, a4);
          a5 = FDOT(bch2(w5[q]), xhv, a5);
        }
      }
      a0 += __shfl_xor(a0,1); a0 += __shfl_xor(a0,2); a0 += __shfl_xor(a0,4);
      a1 += __shfl_xor(a1,1); a1 += __shfl_xor(a1,2); a1 += __shfl_xor(a1,4);
      a2 += __shfl_xor(a2,1); a2 += __shfl_xor(a2,2); a2 += __shfl_xor(a2,4);
      a3 += __shfl_xor(a3,1); a3 += __shfl_xor(a3,2); a3 += __shfl_xor(a3,4);
      a4 += __shfl_xor(a4,1); a4 += __shfl_xor(a4,2); a4 += __shfl_xor(a4,4);
      a5 += __shfl_xor(a5,1); a5 += __shfl_xor(a5,2); a5 += __shfl_xor(a5,4);
      if (oct == 0){
        float gir = gi6[k3]     + a0;
        float giz = gi6[64+k3]  + a1;
        float gin = gi6[128+k3] + a2;
        float ghr = bh6[k3]     + a3;
        float ghz = bh6[64+k3]  + a4;
        float ghn = bh6[128+k3] + a5;
        float r = sigm(gir + ghr);
        float z = sigm(giz + ghz);
        float nn = tanhfast(gin + r*ghn);
        float hv = (1.f - z)*nn + z*hsl[k3];
        hsl[k3] = hv;
        P.rinb[((size_t)t*Bz + b)*G3 + 512 + j*64 + k3] = f2bf(hv);
      }
    }
    __syncthreads();
    if (tid < 32){
      unsigned hp = packh2(hsl[2*tid], hsl[2*tid+1]);
      hn2sl[tid] = hp;
      astore_u32(&P.hxG[b*256 + j*32 + tid], hp);   // f16 h exchange (exact)
    }
    __syncthreads();
    {
      // tgt partial: 512 outputs x own 64-k slice; exchanged as f16 pairs
      float f = 0.f;
      const unsigned* wq = P.Wq2 + (size_t)j*32*512 + tid;
      #pragma unroll 8
      for (int i = 0; i < 32; i++)
        f = FDOT(bch2(wq[(size_t)i*512]), bch2(hn2sl[i]), f);
      float fo = __shfl_xor(f, 1);
      if ((tid & 1) == 0)
        astore_u32(&P.tgtG[((size_t)(b*8+j))*256 + (tid>>1)], packh2(f, fo));
    }
    barn++; gbar(ctr, JB*barn);

    // ---- phase Z: gather h/tgt (u64 f16 loads); attention on LDS rows -------
    if (tid < 128){
      float t0=0.f, t1=0.f, t2=0.f, t3=0.f;
      #pragma unroll
      for (int jj = 0; jj < JB; jj++){
        unsigned long long v = aload_u64(&P.tgtG[((size_t)(b*8+jj))*256 + 2*tid]);
        half2_t p0 = bch2((unsigned)v), p1 = bch2((unsigned)(v >> 32));
        t0 += (float)p0[0]; t1 += (float)p0[1];
        t2 += (float)p1[0]; t3 += (float)p1[1];
      }
      tgt_l[4*tid] = t0; tgt_l[4*tid+1] = t1; tgt_l[4*tid+2] = t2; tgt_l[4*tid+3] = t3;
    } else if (tid < 256){
      int q = tid - 128;   // u64 index: pairs 2q, 2q+1
      unsigned long long v = aload_u64(&P.hxG[b*256 + 2*q]);
      int p0i = 2*q, p1i = 2*q + 1;
      h2p[(p0i>>5)*36 + (p0i&31)] = (unsigned)v;
      h2p[(p1i>>5)*36 + (p1i&31)] = (unsigned)(v >> 32);
    }
    __syncthreads();
    {
      f32x4 t8a = *(const f32x4*)&tgt_l[l*8];
      f32x4 t8b = *(const f32x4*)&tgt_l[l*8 + 4];
      f32x4 ca = (f32x4){0.f,0.f,0.f,0.f}, cb = ca;
      float dsum = 0.f;
      #pragma unroll
      for (int i = 0; i < 7; i++){
        int s = wv + 8*i;
        if (s < SB){
          float cv = covp[s];
          int mkk = mk[s];
          u32x4 pq = pre_l4[s*64 + l];
          f32x4 ba = t8a + cv*wva, bb = t8b + cv*wvb;
          half2_t h0=bch2(pq[0]), h1=bch2(pq[1]), h2v=bch2(pq[2]), h3=bch2(pq[3]);
          float acc;
          acc  = vva[0]*tanhfast((float)h0[0] + ba[0]);
          acc += vva[1]*tanhfast((float)h0[1] + ba[1]);
          acc += vva[2]*tanhfast((float)h1[0] + ba[2]);
          acc += vva[3]*tanhfast((float)h1[1] + ba[3]);
          acc += vvb[0]*tanhfast((float)h2v[0] + bb[0]);
          acc += vvb[1]*tanhfast((float)h2v[1] + bb[1]);
          acc += vvb[2]*tanhfast((float)h3[0] + bb[2]);
          acc += vvb[3]*tanhfast((float)h3[1] + bb[3]);
          #pragma unroll
          for (int m = 1; m < 64; m <<= 1) acc += __shfl_xor(acc, m);
          float en = mkk ? -NEGC : acc;
          float p = __expf(en);
          if (l == 0){
            P.energyAll[((size_t)t*Bz + b)*Sz + sbase + s] = en;
            pl[s] = p;
            dsum += p;
          }
          u32x4 mq = mem_l4[s*64 + l];
          half2_t m0=bch2(mq[0]), m1=bch2(mq[1]), m2=bch2(mq[2]), m3=bch2(mq[3]);
          ca[0] += p*(float)m0[0]; ca[1] += p*(float)m0[1];
          ca[2] += p*(float)m1[0]; ca[3] += p*(float)m1[1];
          cb[0] += p*(float)m2[0]; cb[1] += p*(float)m2[1];
          cb[2] += p*(float)m3[0]; cb[3] += p*(float)m3[1];
        }
      }
      if (l == 0) wsum[wv] = dsum;
      *(f32x4*)&ctxw[wv*Dz + l*8]     = ca;
      *(f32x4*)&ctxw[wv*Dz + l*8 + 4] = cb;
    }
    __syncthreads();
    {
      float ds = wsum[0]+wsum[1]+wsum[2]+wsum[3]+wsum[4]+wsum[5]+wsum[6]+wsum[7];
      float rden = (ds > 0.f) ? 1.f/ds : 0.f;
      float cs = 0.f;
      #pragma unroll
      for (int w = 0; w < 8; w++) cs += ctxw[w*Dz + tid];
      cs *= rden;                         // pre-normalized partial: f16-safe
      float co = __shfl_xor(cs, 1);
      if ((tid & 1) == 0)
        astore_u32(&P.ctxG[((size_t)(b*8+j))*256 + (tid>>1)], packh2(cs, co));
      if (tid == 0) astore_f(&P.denomG[b*8 + j], ds);
    }
    // prefetch gi[t+1] into LDS (overlaps ctx stores; consumed after next gbar)
    if (t+1 < Tz && tid >= 320){
      int idx = tid - 320;
      gi6[idx] = P.giE[((size_t)(t+1)*Bz + b)*G3 + (idx>>6)*512 + j*64 + (idx&63)];
    }
  }

  // ---- drain: t=63 scores + ctx ----
  barn++; gbar(ctr, JB*barn);
  {
    if (tid < 8) sden[tid] = aload_f(&P.denomG[b*8 + tid]);
    __syncthreads();
    float invd = 1.f/(sden[0]+sden[1]+sden[2]+sden[3]+sden[4]+sden[5]+sden[6]+sden[7]);
    if (tid < 128 && (tid >> 4) == j){
      float c0=0.f, c1=0.f, c2=0.f, c3=0.f;
      #pragma unroll
      for (int jj = 0; jj < JB; jj++){
        unsigned long long v = aload_u64(&P.ctxG[((size_t)(b*8+jj))*256 + 2*tid]);
        float w = sden[jj];
        half2_t p0 = bch2((unsigned)v), p1 = bch2((unsigned)(v >> 32));
        c0 += w*(float)p0[0]; c1 += w*(float)p0[1];
        c2 += w*(float)p1[0]; c3 += w*(float)p1[1];
      }
      unsigned* rp = (unsigned*)&P.rinb[((size_t)63*Bz + b)*G3 + 1024 + 4*tid];
      rp[0] = f2bf2(c0*invd, c1*invd); rp[1] = f2bf2(c2*invd, c3*invd);
    } else if (tid >= 256 && tid < 256+SB){
      int s = tid - 256;
      P.attn_out[((size_t)63*Bz + b)*Sz + sbase + s] = pl[s]*invd;
    }
  }
}

// ---------------- maxout + cast ---------------------------------------------
__global__ __launch_bounds__(256) void maxout_k(const float* __restrict__ rout,
    unsigned short* __restrict__ mo){
  int m = blockIdx.x, d = threadIdx.x;
  float a = rout[(size_t)m*Dz + 2*d], b = rout[(size_t)m*Dz + 2*d + 1];
  mo[(size_t)m*256 + d] = f2bf(fmaxf(a, b));
}

// ---------------- OOV fill ---------------------------------------------------
__global__ __launch_bounds__(64) void oov_fill(float* __restrict__ out, int Vext){
  int m = blockIdx.x;
  int b = m & 31, t = m >> 5;
  size_t base = (size_t)(b*Tz + t) * Vext;
  for (int v = VOC + threadIdx.x; v < Vext; v += 64)
    out[base + v] = -NEGC;
}

// ---------------- pointer scatter -------------------------------------------
__global__ __launch_bounds__(256) void scatter_k(const int* __restrict__ ext,
    const float* __restrict__ energyAll, float* __restrict__ out, int Vext){
  __shared__ int ex[Sz];
  __shared__ float en[Sz];
  int m = blockIdx.x;
  int t = m >> 5, b = m & 31;
  int tid = threadIdx.x;
  for (int s = tid; s < Sz; s += 256){
    ex[s] = ext[b*Sz + s];
    en[s] = energyAll[(size_t)m*Sz + s];
  }
  __syncthreads();
  size_t base = (size_t)(b*Tz + t) * Vext;
  for (int s = tid; s < Sz; s += 256){
    int v = ex[s];
    float mv = -3.4e38f; int idx = -1;
    for (int s2 = 0; s2 < Sz; s2++){
      if (ex[s2] == v && en[s2] > mv){ mv = en[s2]; idx = s2; }
    }
    if (idx == s && mv != -NEGC){
      if (v < VOC){
        float w = out[base + v] + mv;
        out[base + v] = (w == 0.f) ? -NEGC : w;
      } else {
        out[base + v] = (mv == 0.f) ? -NEGC : mv;
      }
    }
  }
}

// ============================================================================
extern "C" void kernel_launch(void* const* d_in, const int* in_sizes, int n_in,
                              void* d_out, int out_size, void* d_ws, size_t ws_size,
                              hipStream_t stream){
  const float* emb     = (const float*)d_in[0];
  const float* enc0    = (const float*)d_in[1];
  const float* mem     = (const float*)d_in[2];
  const float* W_trans = (const float*)d_in[3];
  const float* b_trans = (const float*)d_in[4];
  const float* W_ih    = (const float*)d_in[5];
  const float* W_hh    = (const float*)d_in[6];
  const float* b_ih    = (const float*)d_in[7];
  const float* b_hh    = (const float*)d_in[8];
  const float* W_pre   = (const float*)d_in[9];
  const float* b_pre   = (const float*)d_in[10];
  const float* W_q     = (const float*)d_in[11];
  const float* W_cov   = (const float*)d_in[12];
  const float* v_att   = (const float*)d_in[13];
  const float* W_ro    = (const float*)d_in[14];
  const float* b_ro    = (const float*)d_in[15];
  const float* W_logit = (const float*)d_in[16];
  const float* b_logit = (const float*)d_in[17];
  const int*   ext     = (const int*)d_in[18];
  const unsigned char* maskp = (const unsigned char*)d_in[19];
  float* out = (float*)d_out;

  const int Vext = (out_size - 2*Tz*Bz*Sz) / (Bz*Tz);

  char* ws = (char*)d_ws;
  size_t off = 0;
  auto alloc = [&](size_t bytes)->void*{
    void* p = ws + off;
    off += (bytes + 255) & ~(size_t)255;
    return p;
  };
  float* giE         = (float*)alloc((size_t)Tz*Bz*G3*4);
  unsigned* Wg       = (unsigned*)alloc((size_t)786432*4);
  unsigned* Wq2      = (unsigned*)alloc((size_t)131072*4);
  unsigned short* pre2 = (unsigned short*)alloc((size_t)Bz*Sz*Dz*2);
  unsigned short* mem2 = (unsigned short*)alloc((size_t)Bz*Sz*Dz*2);
  unsigned short* emb2 = (unsigned short*)alloc((size_t)Tz*Bz*Dz*2);
  unsigned short* Wih2 = (unsigned short*)alloc((size_t)G3*Dz*2);
  unsigned short* Wpre2= (unsigned short*)alloc((size_t)Dz*Dz*2);
  float* hb          = (float*)alloc((size_t)Bz*Dz*4);
  unsigned* hxG      = (unsigned*)alloc((size_t)Bz*256*4);
  unsigned* tgtG     = (unsigned*)alloc((size_t)Bz*JB*256*4);
  unsigned* ctxG     = (unsigned*)alloc((size_t)Bz*JB*256*4);
  float* denomG      = (float*)alloc((size_t)Bz*JB*4);
  unsigned* ctr      = (unsigned*)alloc((size_t)Bz*16*4);
  float* energyAll   = (float*)alloc((size_t)Tz*Bz*Sz*4);
  float* rout        = (float*)alloc((size_t)Tz*Bz*Dz*4);
  unsigned short* rin_bf = (unsigned short*)alloc((size_t)Tz*Bz*G3*2);
  unsigned short* Wro_bf = (unsigned short*)alloc((size_t)Dz*G3*2);
  unsigned short* mo_bf  = (unsigned short*)alloc((size_t)Tz*Bz*256*2);
  unsigned short* Wl_bf  = (unsigned short*)alloc((size_t)VOC*256*2);

  float* attn_out = out + (size_t)Bz*Tz*Vext;
  float* covh_out = attn_out + (size_t)Tz*Bz*Sz;

  // -------- phase 0: precompute --------
  repack_emb<<<Tz*Bz, 128, 0, stream>>>(emb, emb2, rin_bf);
  wgj_pack<<<3072, 256, 0, stream>>>(W_ih, W_hh, Wg);
  wq2_pack<<<512, 256, 0, stream>>>(W_q, Wq2);
  zero_u32<<<2, 256, 0, stream>>>(ctr, Bz*16);
  cast_f16<<<2048, 256, 0, stream>>>(mem, mem2, Bz*Sz*Dz);
  cast_f16_str<<<1024, 256, 0, stream>>>(W_ih, 1024, Wih2, 512, G3*Dz);
  cast_f16<<<512, 256, 0, stream>>>(W_pre, (unsigned short*)Wpre2, Dz*Dz);
  gemm_f32<<<dim3(1, Dz/64), 256, 0, stream>>>(enc0, Dz, W_trans, Dz, b_trans, hb, Dz, Bz, Dz, Dz);
  mfma_f16k<<<dim3(Tz*Bz/128, G3/128), 256, 0, stream>>>(emb2, Dz, Wih2, Dz, b_ih,
                                                         giE, G3, Dz, 0);
  mfma_f16k<<<dim3(Bz*Sz/128, Dz/128), 256, 0, stream>>>(mem2, Dz, Wpre2, Dz, b_pre,
                                                         pre2, Dz, Dz, 2);
  cast_bf<<<1024, 256, 0, stream>>>(W_ro, Wro_bf, Dz*G3);
  cast_bf<<<2048, 256, 0, stream>>>(W_logit, Wl_bf, VOC*256);

  // -------- phase A: 256-block cooperative kernel, f16-packed exchange -------
  PA P;
  P.Wg = Wg; P.Wq2 = Wq2; P.giE = giE; P.b_hh = b_hh;
  P.pre2 = pre2; P.mem2 = mem2; P.mask = maskp; P.v_att = v_att; P.w_cov = W_cov;
  P.hb = hb; P.hxG = hxG; P.tgtG = tgtG; P.ctxG = ctxG; P.denomG = denomG;
  P.ctr = ctr; P.energyAll = energyAll; P.rinb = rin_bf;
  P.attn_out = attn_out; P.covh_out = covh_out;
  void* kargs[] = { (void*)&P };
  hipLaunchCooperativeKernel((void*)step_all, dim3(Bz*JB), dim3(512), kargs, 0, stream);

  // -------- phase B: batched readout -> maxout -> logits -> pointer --------
  mfma_bf16<<<dim3(Tz*Bz/128, Dz/128), 256, 0, stream>>>(rin_bf, G3, Wro_bf, G3, b_ro,
                                                         rout, Dz, G3, 0, 0);
  maxout_k<<<Tz*Bz, 256, 0, stream>>>(rout, mo_bf);
  mfma_bf16<<<dim3(Tz*Bz/128, VOC/128), 256, 0, stream>>>(mo_bf, 256, Wl_bf, 256, b_logit,
                                                          out, VOC, 256, 1, Vext);
  oov_fill<<<Tz*Bz, 64, 0, stream>>>(out, Vext);
  scatter_k<<<Tz*Bz, 256, 0, stream>>>(ext, energyAll, out, Vext);
  (void)in_sizes; (void)n_in; (void)ws_size;
}